// Round 6
// baseline (270.877 us; speedup 1.0000x reference)
//
#include <hip/hip_runtime.h>
#include <hip/hip_bf16.h>
#include <stdint.h>

typedef __attribute__((ext_vector_type(8))) short bf16x8;
typedef __attribute__((ext_vector_type(4))) float f32x4;

// ---- bf16 pack via native v_cvt_pk_bf16_f32 (RNE) ----
__device__ __forceinline__ bf16x8 pack2(float4 a, float4 b) {
    union { bf16x8 v; __hip_bfloat162 h[4]; } r;
    r.h[0] = __float22bfloat162_rn(make_float2(a.x, a.y));
    r.h[1] = __float22bfloat162_rn(make_float2(a.z, a.w));
    r.h[2] = __float22bfloat162_rn(make_float2(b.x, b.y));
    r.h[3] = __float22bfloat162_rn(make_float2(b.z, b.w));
    return r.v;
}
__device__ __forceinline__ bf16x8 addpack(bf16x8 ib, float4 a, float4 b) {
    union { bf16x8 v; __hip_bfloat162 h[4]; } s; s.v = ib;
    float2 f0 = __bfloat1622float2(s.h[0]);
    float2 f1 = __bfloat1622float2(s.h[1]);
    float2 f2 = __bfloat1622float2(s.h[2]);
    float2 f3 = __bfloat1622float2(s.h[3]);
    union { bf16x8 v; __hip_bfloat162 h[4]; } r;
    r.h[0] = __float22bfloat162_rn(make_float2(f0.x + a.x, f0.y + a.y));
    r.h[1] = __float22bfloat162_rn(make_float2(f1.x + a.z, f1.y + a.w));
    r.h[2] = __float22bfloat162_rn(make_float2(f2.x + b.x, f2.y + b.y));
    r.h[3] = __float22bfloat162_rn(make_float2(f3.x + b.z, f3.y + b.w));
    return r.v;
}
__device__ __forceinline__ float tanh_fast(float x) {
    float e = __expf(2.0f * x);
    return 1.0f - 2.0f / (e + 1.0f);
}
#define MFMA16(a, b, c) __builtin_amdgcn_mfma_f32_16x16x32_bf16((a), (b), (c), 0, 0, 0)

// =========================================================================
// Kernel 1 (tiny prep): Wq,Wk,Wv -> bf16 B-fragment chunks in ws, layout
// [mat][c][n] (c = k-chunk 0..15, n = out-col 0..127) so a wave's B-frag
// load (fixed c per quad, n = nt*16+l15) coalesces into 4x256B segments.
// Also bk' = bk + Wk @ attr.
// =========================================================================
__global__ void finerec_prep(
    const float* __restrict__ attr,
    const float* __restrict__ Wq, const float* __restrict__ Wk,
    const float* __restrict__ bk, const float* __restrict__ Wv,
    float* __restrict__ bkp_ws, short* __restrict__ wf_ws)
{
    if (blockIdx.x == 24) {   // bk' = bk + Wk @ attr
        int n = threadIdx.x;
        if (n < 128) {
            const float* wr = Wk + n * 128;
            float s = bk[n];
            for (int k = 0; k < 128; k += 4) {
                float4 w4 = *(const float4*)(wr + k);
                float4 a4 = *(const float4*)(attr + k);
                s += w4.x * a4.x + w4.y * a4.y + w4.z * a4.z + w4.w * a4.w;
            }
            bkp_ws[n] = s;
        }
        return;
    }
    const int g = blockIdx.x * 256 + threadIdx.x;   // 0..6143
    const int mat = g >> 11, rem = g & 2047, c = rem >> 7, n = rem & 127;
    const float* W = (mat == 0) ? Wq : ((mat == 1) ? Wk : Wv);
    const float* src = W + n * 128 + c * 8;
    ((bf16x8*)wf_ws)[(mat << 11) + (c << 7) + n] =
        pack2(*(const float4*)src, *(const float4*)(src + 4));
}

// =========================================================================
// Kernel 2 (main): one user per wave, NO weight LDS (B-frags streamed from
// the precast ws buffer via L1/L2 — shared by every wave on the device),
// no __syncthreads anywhere. q computed inline via row-0 MFMA trick.
// Rolled nt-loops bound register pressure (no spill).
// =========================================================================
__global__ __launch_bounds__(256, 4) void finerec_main(
    const float* __restrict__ item_table, const float* __restrict__ opin_table,
    const float* __restrict__ user_emb,
    const float* __restrict__ bq, const float* __restrict__ bv,
    const int* __restrict__ item_seqs, const int* __restrict__ opin_seqs,
    const float* __restrict__ bkp_ws, const short* __restrict__ wf_ws,
    float* __restrict__ out, int U, int L)
{
    __shared__ float q_lds[4 * 128];   // per-wave q row (intra-wave RAW only)

    const int tid = threadIdx.x;
    const int wv = tid >> 6, lane = tid & 63, l15 = lane & 15, quad = lane >> 4;
    const int u = blockIdx.x * 4 + wv;
    if (u >= U) return;   // wave-uniform; no barriers in this kernel

    const bf16x8* __restrict__ wfv = (const bf16x8*)wf_ws;

    int vi = 0, vo = 0;
    if (lane < L) { vi = item_seqs[u * L + lane]; vo = opin_seqs[u * L + lane]; }
    const unsigned long long mb = __ballot(vi > 0);   // padding mask bits

    // ---- inline q = tanh(user @ Wq^T + bq): user row as A row 0 ----
    {
        const float* up = user_emb + (size_t)u * 128 + quad * 8;
        bf16x8 uq[4];
#pragma unroll
        for (int ks = 0; ks < 4; ++ks) {
            bf16x8 z = {0, 0, 0, 0, 0, 0, 0, 0};
            uq[ks] = (l15 == 0)
                ? pack2(*(const float4*)(up + ks * 32), *(const float4*)(up + ks * 32 + 4))
                : z;
        }
#pragma unroll 1
        for (int nt = 0; nt < 8; ++nt) {
            const int n = nt * 16 + l15;
            f32x4 cq = {0, 0, 0, 0};
#pragma unroll
            for (int ks = 0; ks < 4; ++ks)
                cq = MFMA16(uq[ks], wfv[((ks * 4 + quad) << 7) + n], cq);
            // C row 0 lives in quad==0 (lanes<16), reg 0
            if (lane < 16) q_lds[wv * 128 + nt * 16 + lane] = tanh_fast(cq[0] + bq[nt * 16 + lane]);
        }
    }

    float s0 = 0.0f, s1 = 0.0f;   // this lane's 2 output columns

#pragma unroll 1
    for (int mp = 0; mp < 2; ++mp) {
        const int rb = mp * 32;
        const int idx0 = __shfl(vi, rb + l15);
        const int idx1 = __shfl(vi, rb + 16 + l15);
        const float* p0 = item_table + (size_t)idx0 * 128 + quad * 8;
        const float* p1 = item_table + (size_t)idx1 * 128 + quad * 8;
        bf16x8 a0[4], a1[4];   // A-frags: row = lane&15, k = quad*8+j (+32*ks)
#pragma unroll
        for (int ks = 0; ks < 4; ++ks) {
            a0[ks] = pack2(*(const float4*)(p0 + ks * 32), *(const float4*)(p0 + ks * 32 + 4));
            a1[ks] = pack2(*(const float4*)(p1 + ks * 32), *(const float4*)(p1 + ks * 32 + 4));
        }
        // ---- K pass (attr folded into bk'); rolled nt ----
        float w0[4] = {0, 0, 0, 0}, w1[4] = {0, 0, 0, 0};
#pragma unroll 1
        for (int nt = 0; nt < 8; ++nt) {
            const int n = nt * 16 + l15;
            f32x4 c0 = {0, 0, 0, 0}, c1 = {0, 0, 0, 0};
#pragma unroll
            for (int ks = 0; ks < 4; ++ks) {
                bf16x8 wf = wfv[(1 << 11) + ((ks * 4 + quad) << 7) + n];
                c0 = MFMA16(a0[ks], wf, c0);
                c1 = MFMA16(a1[ks], wf, c1);
            }
            const float qv  = q_lds[wv * 128 + nt * 16 + l15];
            const float bkv = bkp_ws[nt * 16 + l15];
#pragma unroll
            for (int r = 0; r < 4; ++r) {
                w0[r] += qv * tanh_fast(c0[r] + bkv);
                w1[r] += qv * tanh_fast(c1[r] + bkv);
            }
        }
        // ---- w: reduce over 16 cols within quad + padding mask ----
#pragma unroll
        for (int r = 0; r < 4; ++r) {
            float t0 = w0[r], t1 = w1[r];
            t0 += __shfl_xor(t0, 1); t0 += __shfl_xor(t0, 2);
            t0 += __shfl_xor(t0, 4); t0 += __shfl_xor(t0, 8);
            t1 += __shfl_xor(t1, 1); t1 += __shfl_xor(t1, 2);
            t1 += __shfl_xor(t1, 4); t1 += __shfl_xor(t1, 8);
            w0[r] = ((mb >> (rb + quad * 4 + r)) & 1ull)      ? t0 : 0.0f;
            w1[r] = ((mb >> (rb + 16 + quad * 4 + r)) & 1ull) ? t1 : 0.0f;
        }
        // ---- v_in = item + opin (reuse item frags, no re-gather) ----
        const int od0 = __shfl(vo, rb + l15);
        const int od1 = __shfl(vo, rb + 16 + l15);
        const float* o0p = opin_table + (size_t)od0 * 128 + quad * 8;
        const float* o1p = opin_table + (size_t)od1 * 128 + quad * 8;
#pragma unroll
        for (int ks = 0; ks < 4; ++ks) {
            a0[ks] = addpack(a0[ks], *(const float4*)(o0p + ks * 32), *(const float4*)(o0p + ks * 32 + 4));
            a1[ks] = addpack(a1[ks], *(const float4*)(o1p + ks * 32), *(const float4*)(o1p + ks * 32 + 4));
        }
        // ---- V pass + weighted aggregation; rolled nt, select-accumulate ----
#pragma unroll 1
        for (int nt = 0; nt < 8; ++nt) {
            const int n = nt * 16 + l15;
            f32x4 c0 = {0, 0, 0, 0}, c1 = {0, 0, 0, 0};
#pragma unroll
            for (int ks = 0; ks < 4; ++ks) {
                bf16x8 wf = wfv[(2 << 11) + ((ks * 4 + quad) << 7) + n];
                c0 = MFMA16(a0[ks], wf, c0);
                c1 = MFMA16(a1[ks], wf, c1);
            }
            const float bvv = bv[nt * 16 + l15];
            float acc = 0.0f;
#pragma unroll
            for (int r = 0; r < 4; ++r) {
                acc += w0[r] * tanh_fast(c0[r] + bvv);
                acc += w1[r] * tanh_fast(c1[r] + bvv);
            }
            acc += __shfl_xor(acc, 16);   // sum the 4 row-quads
            acc += __shfl_xor(acc, 32);   // -> full col sum in every lane
            const bool mine = (quad == (nt >> 1));
            s0 += (mine && !(nt & 1)) ? acc : 0.0f;
            s1 += (mine &&  (nt & 1)) ? acc : 0.0f;
        }
    }
    out[u * 128 + quad * 32 + l15]      = s0;   // col = (2*quad)*16 + l15
    out[u * 128 + quad * 32 + 16 + l15] = s1;   // col = (2*quad+1)*16 + l15
}

extern "C" void kernel_launch(void* const* d_in, const int* in_sizes, int n_in,
                              void* d_out, int out_size, void* d_ws, size_t ws_size,
                              hipStream_t stream) {
    const float* item_table = (const float*)d_in[0];
    const float* opin_table = (const float*)d_in[1];
    const float* user_emb   = (const float*)d_in[2];
    const float* attr       = (const float*)d_in[3];
    const float* Wq = (const float*)d_in[4];
    const float* bq = (const float*)d_in[5];
    const float* Wk = (const float*)d_in[6];
    const float* bk = (const float*)d_in[7];
    const float* Wv = (const float*)d_in[8];
    const float* bv = (const float*)d_in[9];
    const int* item_seqs = (const int*)d_in[10];
    const int* opin_seqs = (const int*)d_in[11];
    float* out = (float*)d_out;

    const int U = in_sizes[2] / 128;      // 10000
    const int L = in_sizes[10] / U;       // 50

    short* wf_ws  = (short*)d_ws;                       // 6144 x 16B bf16 chunks
    float* bkp_ws = (float*)((char*)d_ws + 6144 * 16);  // [128] f32

    finerec_prep<<<25, 256, 0, stream>>>(attr, Wq, Wk, bk, Wv, bkp_ws, wf_ws);

    const int grid = (U + 3) / 4;
    finerec_main<<<grid, 256, 0, stream>>>(
        item_table, opin_table, user_emb, bq, bv, item_seqs, opin_seqs,
        bkp_ws, wf_ws, out, U, L);
}